// Round 1
// baseline (241.988 us; speedup 1.0000x reference)
//
#include <hip/hip_runtime.h>
#include <stdint.h>

// ---------------------------------------------------------------------------
// GraphRec forward, MI355X. Pipeline:
//  K1 k_mlp      : e_r + 2-layer MLPs -> Uh,Vh (f32) + blocked bf16 copies
//  K3 k_gemm     : P_I = R[bu]@Vh, P_S = S[bu]@Uh, Q = R^T@Uh  (bf16 MFMA,
//                  split-K=4 partials, no LDS, no atomics)
//  S1 k_scoreAM  : pre-softmax scores sA (cat(Vb,Ub)) and sM (cat(Ub,Vb))
//  S2 k_softmax2 : softmax over batch for A and M
//  S3 k_HI_scoreB: H_I = relu((A.P_I)@W_I+b) ; sB scores (cat(H_I,Ub))
//  S4 k_softmax2 : softmax B
//  S5 k_HS_H     : H_S = relu((B.P_S)@W_Sm+b); H = MLP(cat(H_I,H_S))
//  S6 k_Z_G      : Z = relu((M.Q[bi])@W_Z+b); G = MLP(cat(H,Z)) -> d_out
// ---------------------------------------------------------------------------

typedef short bf16x8 __attribute__((ext_vector_type(8)));
typedef float f32x4 __attribute__((ext_vector_type(4)));

__device__ __forceinline__ unsigned f2bf1(float f) {
    unsigned x = __float_as_uint(f);
    return (x + 0x7FFFu + ((x >> 16) & 1u)) >> 16;   // RNE f32->bf16
}

__device__ __forceinline__ float wsum(float v) {
    #pragma unroll
    for (int o = 32; o; o >>= 1) v += __shfl_xor(v, o);
    return v;
}

// ---------------------------------------------------------------- K1: MLPs
__global__ __launch_bounds__(256) void k_mlp(
    const float* __restrict__ U, const float* __restrict__ V,
    const float* __restrict__ w_r, const float* __restrict__ b_r,
    const float* __restrict__ Wu0, const float* __restrict__ bu0,
    const float* __restrict__ Wu1, const float* __restrict__ bu1,
    const float* __restrict__ Wv0, const float* __restrict__ bv0,
    const float* __restrict__ Wv1, const float* __restrict__ bv1,
    float* __restrict__ Uh, float* __restrict__ Vh,
    unsigned short* __restrict__ Uhb, unsigned short* __restrict__ Vhb)
{
    int gt = blockIdx.x * 256 + threadIdx.x;
    int wid = gt >> 6;
    int lane = gt & 63;

    // e_r = [1..5] @ w_r + b_r   (lane = d)
    float er = b_r[lane];
    #pragma unroll
    for (int s = 0; s < 5; ++s) er += (float)(s + 1) * w_r[s * 64 + lane];

    const int isV = (wid >= 1024);
    const float* X  = isV ? V   : U;
    const float* W0 = isV ? Wv0 : Wu0;
    const float* B0 = isV ? bv0 : bu0;
    const float* W1 = isV ? Wv1 : Wu1;
    const float* B1 = isV ? bv1 : bu1;
    float* Hout          = isV ? Vh  : Uh;
    unsigned short* Hb   = isV ? Vhb : Uhb;
    int r0 = (wid & 1023) * 8;

    float x[8];
    #pragma unroll
    for (int j = 0; j < 8; ++j) x[j] = X[(r0 + j) * 64 + lane];

    // e_r contribution to layer0 is row-independent: hoist
    float h0c = B0[lane];
    for (int k = 0; k < 64; ++k) h0c += __shfl(er, k) * W0[(64 + k) * 64 + lane];

    float h0[8];
    #pragma unroll
    for (int j = 0; j < 8; ++j) h0[j] = h0c;
    for (int k = 0; k < 64; ++k) {
        float wv = W0[k * 64 + lane];
        #pragma unroll
        for (int j = 0; j < 8; ++j) h0[j] += __shfl(x[j], k) * wv;
    }
    #pragma unroll
    for (int j = 0; j < 8; ++j) h0[j] = fmaxf(h0[j], 0.f);

    float h1[8];
    #pragma unroll
    for (int j = 0; j < 8; ++j) h1[j] = B1[lane];
    for (int k = 0; k < 64; ++k) {
        float wv = W1[k * 64 + lane];
        #pragma unroll
        for (int j = 0; j < 8; ++j) h1[j] += __shfl(h0[j], k) * wv;
    }
    #pragma unroll
    for (int j = 0; j < 8; ++j) {
        h1[j] = fmaxf(h1[j], 0.f);
        Hout[(r0 + j) * 64 + lane] = h1[j];
    }
    // blocked bf16 store: element (r0+j, d) at (r0>>3)*512 + (d>>4)*128 + (d&15)*8 + j
    unsigned pw[4];
    #pragma unroll
    for (int q = 0; q < 4; ++q) pw[q] = f2bf1(h1[2*q]) | (f2bf1(h1[2*q+1]) << 16);
    unsigned short* dst = Hb + (size_t)(r0 >> 3) * 512 + (lane >> 4) * 128 + (lane & 15) * 8;
    *(uint4*)dst = make_uint4(pw[0], pw[1], pw[2], pw[3]);
}

// --------------------------------------------------------------- K3: GEMMs
// blocks 0..255  : P_I  (tile=bid&63, kz=bid>>6)      A = R[bu rows]
// blocks 256..511: P_S                                 A = S[bu rows]
// blocks 512..1023: Q = R^T @ Uh (tile=q&127, kz=q>>7) A = R columns
__global__ __launch_bounds__(256) void k_gemm(
    const float* __restrict__ R, const float* __restrict__ S,
    const int* __restrict__ bu,
    const unsigned short* __restrict__ Uhb, const unsigned short* __restrict__ Vhb,
    float* __restrict__ PpI, float* __restrict__ PpS, float* __restrict__ Qp)
{
    int bid = blockIdx.x;
    int tid = threadIdx.x;
    int w = tid >> 6;
    int l = tid & 63;
    int lg = l >> 4, lr = l & 15;

    f32x4 acc[4] = {};

    if (bid < 512) {
        const int isS = bid >= 256;
        int q = bid & 255;
        int tile = q & 63, kz = q >> 6;
        int brow = tile * 64 + w * 16 + lr;
        int ridx = bu[brow];
        const float* A = (isS ? S : R) + (size_t)ridx * 8192 + kz * 2048 + lg * 8;
        const unsigned short* Bb = (isS ? Uhb : Vhb) + (size_t)((kz * 2048) >> 3) * 512 + lr * 8;
        #pragma unroll 2
        for (int ks = 0; ks < 64; ++ks) {
            f32x4 a0 = *(const f32x4*)(A + ks * 32);
            f32x4 a1 = *(const f32x4*)(A + ks * 32 + 4);
            union { bf16x8 v; unsigned u[4]; } af;
            af.u[0] = f2bf1(a0.x) | (f2bf1(a0.y) << 16);
            af.u[1] = f2bf1(a0.z) | (f2bf1(a0.w) << 16);
            af.u[2] = f2bf1(a1.x) | (f2bf1(a1.y) << 16);
            af.u[3] = f2bf1(a1.z) | (f2bf1(a1.w) << 16);
            const unsigned short* bp = Bb + (size_t)(ks * 4 + lg) * 512;
            #pragma unroll
            for (int c = 0; c < 4; ++c) {
                bf16x8 bf = *(const bf16x8*)(bp + c * 128);
                acc[c] = __builtin_amdgcn_mfma_f32_16x16x32_bf16(af.v, bf, acc[c], 0, 0, 0);
            }
        }
        float* out = (isS ? PpS : PpI) + (size_t)(kz * 4096 + tile * 64 + w * 16 + lg * 4) * 64 + lr;
        #pragma unroll
        for (int c = 0; c < 4; ++c) {
            #pragma unroll
            for (int j = 0; j < 4; ++j) out[j * 64 + c * 16] = acc[c][j];
        }
    } else {
        int q = bid - 512;
        int tile = q & 127, kz = q >> 7;
        int icol = tile * 64 + w * 16 + lr;
        int kbase = kz * 2048;
        const float* A = R + (size_t)(kbase + lg * 8) * 8192 + icol;
        const unsigned short* Bb = Uhb + (size_t)(kbase >> 3) * 512 + lr * 8;
        #pragma unroll 2
        for (int ks = 0; ks < 64; ++ks) {
            const float* ap = A + (size_t)ks * 32 * 8192;
            float av[8];
            #pragma unroll
            for (int j = 0; j < 8; ++j) av[j] = ap[(size_t)j * 8192];
            union { bf16x8 v; unsigned u[4]; } af;
            #pragma unroll
            for (int qq = 0; qq < 4; ++qq)
                af.u[qq] = f2bf1(av[2*qq]) | (f2bf1(av[2*qq+1]) << 16);
            const unsigned short* bp = Bb + (size_t)(ks * 4 + lg) * 512;
            #pragma unroll
            for (int c = 0; c < 4; ++c) {
                bf16x8 bf = *(const bf16x8*)(bp + c * 128);
                acc[c] = __builtin_amdgcn_mfma_f32_16x16x32_bf16(af.v, bf, acc[c], 0, 0, 0);
            }
        }
        float* out = Qp + (size_t)(kz * 8192 + tile * 64 + w * 16 + lg * 4) * 64 + lr;
        #pragma unroll
        for (int c = 0; c < 4; ++c) {
            #pragma unroll
            for (int j = 0; j < 4; ++j) out[j * 64 + c * 16] = acc[c][j];
        }
    }
}

// ------------------------------------------------------- S1: scores A and M
__global__ __launch_bounds__(256) void k_scoreAM(
    const int* __restrict__ bu, const int* __restrict__ bi,
    const float* __restrict__ Uh, const float* __restrict__ Vh,
    const float* __restrict__ W1A, const float* __restrict__ b1A,
    const float* __restrict__ w2A, const float* __restrict__ b2A,
    const float* __restrict__ W1M, const float* __restrict__ b1M,
    const float* __restrict__ w2M, const float* __restrict__ b2M,
    float* __restrict__ sA, float* __restrict__ sM)
{
    int gt = blockIdx.x * 256 + threadIdx.x;
    int wid = gt >> 6, lane = gt & 63;
    int b0 = wid * 4;
    float ub[4], vb[4];
    #pragma unroll
    for (int j = 0; j < 4; ++j) {
        ub[j] = Uh[(size_t)bu[b0 + j] * 64 + lane];
        vb[j] = Vh[(size_t)bi[b0 + j] * 64 + lane];
    }
    float hA[4], hM[4];
    #pragma unroll
    for (int j = 0; j < 4; ++j) { hA[j] = b1A[lane]; hM[j] = b1M[lane]; }
    for (int k = 0; k < 64; ++k) {
        float wa0 = W1A[k * 64 + lane], wa1 = W1A[(64 + k) * 64 + lane];
        float wm0 = W1M[k * 64 + lane], wm1 = W1M[(64 + k) * 64 + lane];
        #pragma unroll
        for (int j = 0; j < 4; ++j) {
            float sv = __shfl(vb[j], k), su = __shfl(ub[j], k);
            hA[j] += sv * wa0 + su * wa1;   // cat(Vb, Ub)
            hM[j] += su * wm0 + sv * wm1;   // cat(Ub, Vb)
        }
    }
    float w2a = w2A[lane], w2m = w2M[lane];
    #pragma unroll
    for (int j = 0; j < 4; ++j) {
        float sa = wsum(fmaxf(hA[j], 0.f) * w2a);
        float sm = wsum(fmaxf(hM[j], 0.f) * w2m);
        if (lane == 0) { sA[b0 + j] = sa + b2A[0]; sM[b0 + j] = sm + b2M[0]; }
    }
}

// --------------------------------------------------------------- softmax(4096)
__device__ __forceinline__ void softmax4096(const float* __restrict__ s, float* __restrict__ wout) {
    __shared__ float red[16];
    __shared__ float red2[16];
    int t = threadIdx.x, lane = t & 63, wv = t >> 6;
    float v[4];
    #pragma unroll
    for (int j = 0; j < 4; ++j) v[j] = s[t + 1024 * j];
    float m = fmaxf(fmaxf(v[0], v[1]), fmaxf(v[2], v[3]));
    #pragma unroll
    for (int o = 32; o; o >>= 1) m = fmaxf(m, __shfl_xor(m, o));
    if (lane == 0) red[wv] = m;
    __syncthreads();
    float mm = red[0];
    #pragma unroll
    for (int i = 1; i < 16; ++i) mm = fmaxf(mm, red[i]);
    float e[4], lsum = 0.f;
    #pragma unroll
    for (int j = 0; j < 4; ++j) { e[j] = __expf(v[j] - mm); lsum += e[j]; }
    lsum = wsum(lsum);
    if (lane == 0) red2[wv] = lsum;
    __syncthreads();
    float ss = 0.f;
    #pragma unroll
    for (int i = 0; i < 16; ++i) ss += red2[i];
    float inv = 1.0f / ss;
    #pragma unroll
    for (int j = 0; j < 4; ++j) wout[t + 1024 * j] = e[j] * inv;
}

__global__ __launch_bounds__(1024) void k_softmax2(
    const float* __restrict__ s0, float* __restrict__ w0,
    const float* __restrict__ s1, float* __restrict__ w1)
{
    if (blockIdx.x == 0) softmax4096(s0, w0);
    else                 softmax4096(s1, w1);
}

// ------------------------------------------------- S3: H_I and B-scores
__global__ __launch_bounds__(256) void k_HI_scoreB(
    const float* __restrict__ PpI, const float* __restrict__ wA,
    const int* __restrict__ bu, const float* __restrict__ Uh,
    const float* __restrict__ W_I, const float* __restrict__ b_I,
    const float* __restrict__ W1B, const float* __restrict__ b1B,
    const float* __restrict__ w2B, const float* __restrict__ b2B,
    float* __restrict__ HI, float* __restrict__ sB)
{
    int gt = blockIdx.x * 256 + threadIdx.x;
    int wid = gt >> 6, lane = gt & 63;
    int b0 = wid * 4;
    float p[4];
    #pragma unroll
    for (int j = 0; j < 4; ++j) {
        int b = b0 + j;
        p[j] = (PpI[(size_t)b * 64 + lane] + PpI[(size_t)(4096 + b) * 64 + lane]
              + PpI[(size_t)(8192 + b) * 64 + lane] + PpI[(size_t)(12288 + b) * 64 + lane]) * wA[b];
    }
    float h[4];
    #pragma unroll
    for (int j = 0; j < 4; ++j) h[j] = b_I[lane];
    for (int k = 0; k < 64; ++k) {
        float wv = W_I[k * 64 + lane];
        #pragma unroll
        for (int j = 0; j < 4; ++j) h[j] += __shfl(p[j], k) * wv;
    }
    float ub[4];
    #pragma unroll
    for (int j = 0; j < 4; ++j) {
        h[j] = fmaxf(h[j], 0.f);
        HI[(size_t)(b0 + j) * 64 + lane] = h[j];
        ub[j] = Uh[(size_t)bu[b0 + j] * 64 + lane];
    }
    float h2[4];
    #pragma unroll
    for (int j = 0; j < 4; ++j) h2[j] = b1B[lane];
    for (int k = 0; k < 64; ++k) {
        float w0 = W1B[k * 64 + lane], w1 = W1B[(64 + k) * 64 + lane];
        #pragma unroll
        for (int j = 0; j < 4; ++j) h2[j] += __shfl(h[j], k) * w0 + __shfl(ub[j], k) * w1;
    }
    float w2 = w2B[lane];
    #pragma unroll
    for (int j = 0; j < 4; ++j) {
        float sv = wsum(fmaxf(h2[j], 0.f) * w2);
        if (lane == 0) sB[b0 + j] = sv + b2B[0];
    }
}

// ------------------------------------------------- S5: H_S then H
__global__ __launch_bounds__(256) void k_HS_H(
    const float* __restrict__ PpS, const float* __restrict__ wB,
    const float* __restrict__ HI,
    const float* __restrict__ W_Sm, const float* __restrict__ b_Sm,
    const float* __restrict__ Wc0, const float* __restrict__ bc0,
    const float* __restrict__ Wc1, const float* __restrict__ bc1,
    float* __restrict__ Hout)
{
    int gt = blockIdx.x * 256 + threadIdx.x;
    int wid = gt >> 6, lane = gt & 63;
    int b0 = wid * 4;
    float p[4];
    #pragma unroll
    for (int j = 0; j < 4; ++j) {
        int b = b0 + j;
        p[j] = (PpS[(size_t)b * 64 + lane] + PpS[(size_t)(4096 + b) * 64 + lane]
              + PpS[(size_t)(8192 + b) * 64 + lane] + PpS[(size_t)(12288 + b) * 64 + lane]) * wB[b];
    }
    float hs[4];
    #pragma unroll
    for (int j = 0; j < 4; ++j) hs[j] = b_Sm[lane];
    for (int k = 0; k < 64; ++k) {
        float wv = W_Sm[k * 64 + lane];
        #pragma unroll
        for (int j = 0; j < 4; ++j) hs[j] += __shfl(p[j], k) * wv;
    }
    float hi[4];
    #pragma unroll
    for (int j = 0; j < 4; ++j) {
        hs[j] = fmaxf(hs[j], 0.f);
        hi[j] = HI[(size_t)(b0 + j) * 64 + lane];
    }
    float h0[4];
    #pragma unroll
    for (int j = 0; j < 4; ++j) h0[j] = bc0[lane];
    for (int k = 0; k < 64; ++k) {
        float w0 = Wc0[k * 64 + lane], w1 = Wc0[(64 + k) * 64 + lane];
        #pragma unroll
        for (int j = 0; j < 4; ++j) h0[j] += __shfl(hi[j], k) * w0 + __shfl(hs[j], k) * w1;
    }
    #pragma unroll
    for (int j = 0; j < 4; ++j) h0[j] = fmaxf(h0[j], 0.f);
    float h1[4];
    #pragma unroll
    for (int j = 0; j < 4; ++j) h1[j] = bc1[lane];
    for (int k = 0; k < 64; ++k) {
        float wv = Wc1[k * 64 + lane];
        #pragma unroll
        for (int j = 0; j < 4; ++j) h1[j] += __shfl(h0[j], k) * wv;
    }
    #pragma unroll
    for (int j = 0; j < 4; ++j) Hout[(size_t)(b0 + j) * 64 + lane] = fmaxf(h1[j], 0.f);
}

// ------------------------------------------------- S6: Z then G (output)
__global__ __launch_bounds__(256) void k_Z_G(
    const float* __restrict__ Qp, const float* __restrict__ wM,
    const int* __restrict__ bi, const float* __restrict__ H,
    const float* __restrict__ W_Z, const float* __restrict__ b_Z,
    const float* __restrict__ Wg0, const float* __restrict__ bg0,
    const float* __restrict__ Wg1, const float* __restrict__ bg1,
    float* __restrict__ G)
{
    int gt = blockIdx.x * 256 + threadIdx.x;
    int wid = gt >> 6, lane = gt & 63;
    int b0 = wid * 4;
    float p[4];
    #pragma unroll
    for (int j = 0; j < 4; ++j) {
        int b = b0 + j;
        int it = bi[b];
        p[j] = (Qp[(size_t)it * 64 + lane] + Qp[(size_t)(8192 + it) * 64 + lane]
              + Qp[(size_t)(16384 + it) * 64 + lane] + Qp[(size_t)(24576 + it) * 64 + lane]) * wM[b];
    }
    float z[4];
    #pragma unroll
    for (int j = 0; j < 4; ++j) z[j] = b_Z[lane];
    for (int k = 0; k < 64; ++k) {
        float wv = W_Z[k * 64 + lane];
        #pragma unroll
        for (int j = 0; j < 4; ++j) z[j] += __shfl(p[j], k) * wv;
    }
    float hr[4];
    #pragma unroll
    for (int j = 0; j < 4; ++j) {
        z[j] = fmaxf(z[j], 0.f);
        hr[j] = H[(size_t)(b0 + j) * 64 + lane];
    }
    float g0[4];
    #pragma unroll
    for (int j = 0; j < 4; ++j) g0[j] = bg0[lane];
    for (int k = 0; k < 64; ++k) {
        float w0 = Wg0[k * 64 + lane], w1 = Wg0[(64 + k) * 64 + lane];
        #pragma unroll
        for (int j = 0; j < 4; ++j) g0[j] += __shfl(hr[j], k) * w0 + __shfl(z[j], k) * w1;
    }
    #pragma unroll
    for (int j = 0; j < 4; ++j) g0[j] = fmaxf(g0[j], 0.f);
    float g1[4];
    #pragma unroll
    for (int j = 0; j < 4; ++j) g1[j] = bg1[lane];
    for (int k = 0; k < 64; ++k) {
        float wv = Wg1[k * 64 + lane];
        #pragma unroll
        for (int j = 0; j < 4; ++j) g1[j] += __shfl(g0[j], k) * wv;
    }
    #pragma unroll
    for (int j = 0; j < 4; ++j) G[(size_t)(b0 + j) * 64 + lane] = fmaxf(g1[j], 0.f);
}

// ---------------------------------------------------------------------------
extern "C" void kernel_launch(void* const* d_in, const int* in_sizes, int n_in,
                              void* d_out, int out_size, void* d_ws, size_t ws_size,
                              hipStream_t stream)
{
    (void)in_sizes; (void)n_in; (void)out_size; (void)ws_size;
    const int*   bu  = (const int*)  d_in[0];
    const int*   bi  = (const int*)  d_in[1];
    const float* R   = (const float*)d_in[2];
    const float* S   = (const float*)d_in[3];
    const float* U   = (const float*)d_in[4];
    const float* V   = (const float*)d_in[5];
    const float* w_r = (const float*)d_in[6];
    const float* b_r = (const float*)d_in[7];
    const float* Wu0 = (const float*)d_in[8];
    const float* bu0 = (const float*)d_in[9];
    const float* Wu1 = (const float*)d_in[10];
    const float* bu1 = (const float*)d_in[11];
    const float* Wv0 = (const float*)d_in[12];
    const float* bv0 = (const float*)d_in[13];
    const float* Wv1 = (const float*)d_in[14];
    const float* bv1 = (const float*)d_in[15];
    const float* Wc0 = (const float*)d_in[16];
    const float* bc0 = (const float*)d_in[17];
    const float* Wc1 = (const float*)d_in[18];
    const float* bc1 = (const float*)d_in[19];
    const float* Wg0 = (const float*)d_in[20];
    const float* bg0 = (const float*)d_in[21];
    const float* Wg1 = (const float*)d_in[22];
    const float* bg1 = (const float*)d_in[23];
    const float* W_I = (const float*)d_in[24];
    const float* b_I = (const float*)d_in[25];
    const float* W_Sm= (const float*)d_in[26];
    const float* b_Sm= (const float*)d_in[27];
    const float* W1A = (const float*)d_in[28];
    const float* b1A = (const float*)d_in[29];
    const float* w2A = (const float*)d_in[30];
    const float* b2A = (const float*)d_in[31];
    const float* W1B = (const float*)d_in[32];
    const float* b1B = (const float*)d_in[33];
    const float* w2B = (const float*)d_in[34];
    const float* b2B = (const float*)d_in[35];
    const float* W1M = (const float*)d_in[36];
    const float* b1M = (const float*)d_in[37];
    const float* w2M = (const float*)d_in[38];
    const float* b2M = (const float*)d_in[39];
    const float* W_Z = (const float*)d_in[40];
    const float* b_Z = (const float*)d_in[41];

    char* ws = (char*)d_ws;
    float*          Uh  = (float*)(ws);                           // 2 MB
    float*          Vh  = (float*)(ws + (2ull << 20));            // 2 MB
    unsigned short* Uhb = (unsigned short*)(ws + (4ull << 20));   // 1 MB
    unsigned short* Vhb = (unsigned short*)(ws + (5ull << 20));   // 1 MB
    float*          PpI = (float*)(ws + (6ull << 20));            // 4 MB
    float*          PpS = (float*)(ws + (10ull << 20));           // 4 MB
    float*          Qp  = (float*)(ws + (14ull << 20));           // 8 MB
    float*          sA  = (float*)(ws + (22ull << 20));
    float*          sM  = sA + 4096;
    float*          sB  = sA + 8192;
    float*          wA  = sA + 12288;
    float*          wM  = sA + 16384;
    float*          wB  = sA + 20480;
    float*          HI  = (float*)(ws + (23ull << 20));           // 1 MB
    float*          Hh  = (float*)(ws + (24ull << 20));           // 1 MB

    k_mlp<<<512, 256, 0, stream>>>(U, V, w_r, b_r, Wu0, bu0, Wu1, bu1,
                                   Wv0, bv0, Wv1, bv1, Uh, Vh, Uhb, Vhb);
    k_gemm<<<1024, 256, 0, stream>>>(R, S, bu, Uhb, Vhb, PpI, PpS, Qp);
    k_scoreAM<<<256, 256, 0, stream>>>(bu, bi, Uh, Vh, W1A, b1A, w2A, b2A,
                                       W1M, b1M, w2M, b2M, sA, sM);
    k_softmax2<<<2, 1024, 0, stream>>>(sA, wA, sM, wM);
    k_HI_scoreB<<<256, 256, 0, stream>>>(PpI, wA, bu, Uh, W_I, b_I,
                                         W1B, b1B, w2B, b2B, HI, sB);
    k_softmax2<<<1, 1024, 0, stream>>>(sB, wB, sB, wB);
    k_HS_H<<<256, 256, 0, stream>>>(PpS, wB, HI, W_Sm, b_Sm, Wc0, bc0, Wc1, bc1, Hh);
    k_Z_G<<<256, 256, 0, stream>>>(Qp, wM, bi, Hh, W_Z, b_Z, Wg0, bg0, Wg1, bg1,
                                   (float*)d_out);
}

// Round 2
// 241.531 us; speedup vs baseline: 1.0019x; 1.0019x over previous
//
#include <hip/hip_runtime.h>
#include <stdint.h>

// ---------------------------------------------------------------------------
// GraphRec forward, MI355X.
//  K1 k_mlp      : e_r + 2-layer MLPs -> Uh,Vh (f32) + blocked bf16 copies
//  K2 k_gemm     : P_I = R[bu]@Vh, P_S = S[bu]@Uh, Q = R^T@Uh  (bf16 MFMA,
//                  split-K partials, register prefetch, no LDS, no atomics)
//  S1 k_scoreAM  : pre-softmax scores sA (cat(Vb,Ub)) and sM (cat(Ub,Vb))
//  S2 k_HI_scoreB: [softmax-A stats in-block] H_I = relu((A.P_I)@W_I+b); sB
//  S3 k_HS_H     : [softmax-B] H_S = relu((B.P_S)@W_Sm+b); H = MLP(cat(H_I,H_S))
//  S4 k_Z_G      : [softmax-M] Z = relu((M.Q[bi])@W_Z+b); G = MLP(cat(H,Z))
// ---------------------------------------------------------------------------

typedef short bf16x8 __attribute__((ext_vector_type(8)));
typedef float f32x4 __attribute__((ext_vector_type(4)));

__device__ __forceinline__ unsigned f2bf1(float f) {
    unsigned x = __float_as_uint(f);
    return (x + 0x7FFFu + ((x >> 16) & 1u)) >> 16;   // RNE f32->bf16
}

__device__ __forceinline__ float wsum(float v) {
    #pragma unroll
    for (int o = 32; o; o >>= 1) v += __shfl_xor(v, o);
    return v;
}

// block-wide softmax stats over a 4096-vector (256-thread block)
__device__ __forceinline__ void block_softmax_stats(const float* __restrict__ s,
                                                    float& m, float& inv) {
    __shared__ float r1[4];
    __shared__ float r2[4];
    int t = threadIdx.x, lane = t & 63, wv = t >> 6;
    float lm = -3.4e38f;
    #pragma unroll
    for (int i = 0; i < 16; ++i) lm = fmaxf(lm, s[t + 256 * i]);
    #pragma unroll
    for (int o = 32; o; o >>= 1) lm = fmaxf(lm, __shfl_xor(lm, o));
    if (lane == 0) r1[wv] = lm;
    __syncthreads();
    m = fmaxf(fmaxf(r1[0], r1[1]), fmaxf(r1[2], r1[3]));
    float ls = 0.f;
    #pragma unroll
    for (int i = 0; i < 16; ++i) ls += __expf(s[t + 256 * i] - m);
    ls = wsum(ls);
    if (lane == 0) r2[wv] = ls;
    __syncthreads();
    inv = 1.f / (r2[0] + r2[1] + r2[2] + r2[3]);
}

// ---------------------------------------------------------------- K1: MLPs
__global__ __launch_bounds__(256) void k_mlp(
    const float* __restrict__ U, const float* __restrict__ V,
    const float* __restrict__ w_r, const float* __restrict__ b_r,
    const float* __restrict__ Wu0, const float* __restrict__ bu0,
    const float* __restrict__ Wu1, const float* __restrict__ bu1,
    const float* __restrict__ Wv0, const float* __restrict__ bv0,
    const float* __restrict__ Wv1, const float* __restrict__ bv1,
    float* __restrict__ Uh, float* __restrict__ Vh,
    unsigned short* __restrict__ Uhb, unsigned short* __restrict__ Vhb)
{
    int gt = blockIdx.x * 256 + threadIdx.x;
    int wid = gt >> 6;
    int lane = gt & 63;

    float er = b_r[lane];
    #pragma unroll
    for (int s = 0; s < 5; ++s) er += (float)(s + 1) * w_r[s * 64 + lane];

    const int isV = (wid >= 2048);
    const float* X  = isV ? V   : U;
    const float* W0 = isV ? Wv0 : Wu0;
    const float* B0 = isV ? bv0 : bu0;
    const float* W1 = isV ? Wv1 : Wu1;
    const float* B1 = isV ? bv1 : bu1;
    float* Hout          = isV ? Vh  : Uh;
    unsigned short* Hb   = isV ? Vhb : Uhb;
    int r0 = (wid & 2047) * 4;

    float x[4];
    #pragma unroll
    for (int j = 0; j < 4; ++j) x[j] = X[(r0 + j) * 64 + lane];

    float h0c = B0[lane];
    for (int k = 0; k < 64; ++k) h0c += __shfl(er, k) * W0[(64 + k) * 64 + lane];

    float h0[4];
    #pragma unroll
    for (int j = 0; j < 4; ++j) h0[j] = h0c;
    for (int k = 0; k < 64; ++k) {
        float wv = W0[k * 64 + lane];
        #pragma unroll
        for (int j = 0; j < 4; ++j) h0[j] += __shfl(x[j], k) * wv;
    }
    #pragma unroll
    for (int j = 0; j < 4; ++j) h0[j] = fmaxf(h0[j], 0.f);

    float h1[4];
    #pragma unroll
    for (int j = 0; j < 4; ++j) h1[j] = B1[lane];
    for (int k = 0; k < 64; ++k) {
        float wv = W1[k * 64 + lane];
        #pragma unroll
        for (int j = 0; j < 4; ++j) h1[j] += __shfl(h0[j], k) * wv;
    }
    #pragma unroll
    for (int j = 0; j < 4; ++j) {
        h1[j] = fmaxf(h1[j], 0.f);
        Hout[(r0 + j) * 64 + lane] = h1[j];
    }
    // blocked bf16: element (r,d) at (r>>3)*512 + (d>>4)*128 + (d&15)*8 + (r&7)
    unsigned pw[2];
    #pragma unroll
    for (int q = 0; q < 2; ++q) pw[q] = f2bf1(h1[2*q]) | (f2bf1(h1[2*q+1]) << 16);
    unsigned short* dst = Hb + (size_t)(r0 >> 3) * 512 + (lane >> 4) * 128
                        + (lane & 15) * 8 + (r0 & 7);
    *(uint2*)dst = make_uint2(pw[0], pw[1]);
}

// --------------------------------------------------------------- K2: GEMMs
// blocks [0, gP)        : P_I (tile=q&63, kz=q>>6)   A = R[bu rows]
// blocks [gP, 2gP)      : P_S                        A = S[bu rows]
// blocks [2gP, 2gP+gQ)  : Q = R^T@Uh (tile=q&127, kz=q>>7), A = R columns
__global__ __launch_bounds__(256, 8) void k_gemm(
    const float* __restrict__ R, const float* __restrict__ S,
    const int* __restrict__ bu,
    const unsigned short* __restrict__ Uhb, const unsigned short* __restrict__ Vhb,
    float* __restrict__ PpI, float* __restrict__ PpS, float* __restrict__ Qp,
    int nkz, int klen)
{
    int bid = blockIdx.x;
    int tid = threadIdx.x;
    int w = tid >> 6;
    int l = tid & 63;
    int lg = l >> 4, lr = l & 15;
    int kiters = klen >> 5;
    int gP = nkz << 6;

    f32x4 acc[4] = {};

    if (bid < 2 * gP) {
        const int isS = bid >= gP;
        int q = isS ? bid - gP : bid;
        int tile = q & 63, kz = q >> 6;
        int brow = tile * 64 + w * 16 + lr;
        int ridx = bu[brow];
        const float* A = (isS ? S : R) + (size_t)ridx * 8192 + kz * klen + lg * 8;
        const unsigned short* Bb = (isS ? Uhb : Vhb)
                                 + (size_t)((kz * klen) >> 3) * 512 + lr * 8;
        f32x4 c0 = ((const f32x4*)A)[0];
        f32x4 c1 = ((const f32x4*)A)[1];
        #pragma unroll 2
        for (int ks = 0; ks < kiters; ++ks) {
            int nxt = (ks + 1 < kiters) ? ks + 1 : ks;
            f32x4 n0 = ((const f32x4*)(A + nxt * 32))[0];
            f32x4 n1 = ((const f32x4*)(A + nxt * 32))[1];
            union { bf16x8 v; unsigned u[4]; } af;
            af.u[0] = f2bf1(c0.x) | (f2bf1(c0.y) << 16);
            af.u[1] = f2bf1(c0.z) | (f2bf1(c0.w) << 16);
            af.u[2] = f2bf1(c1.x) | (f2bf1(c1.y) << 16);
            af.u[3] = f2bf1(c1.z) | (f2bf1(c1.w) << 16);
            const unsigned short* bp = Bb + (size_t)(ks * 4 + lg) * 512;
            #pragma unroll
            for (int c = 0; c < 4; ++c) {
                bf16x8 bf = *(const bf16x8*)(bp + c * 128);
                acc[c] = __builtin_amdgcn_mfma_f32_16x16x32_bf16(af.v, bf, acc[c], 0, 0, 0);
            }
            c0 = n0; c1 = n1;
        }
        float* out = (isS ? PpS : PpI)
                   + (size_t)(kz * 4096 + tile * 64 + w * 16 + lg * 4) * 64 + lr;
        #pragma unroll
        for (int c = 0; c < 4; ++c) {
            #pragma unroll
            for (int j = 0; j < 4; ++j) out[j * 64 + c * 16] = acc[c][j];
        }
    } else {
        int q = bid - 2 * gP;
        int tile = q & 127, kz = q >> 7;
        int icol = tile * 64 + w * 16 + lr;
        const float* A = R + (size_t)(kz * klen + lg * 8) * 8192 + icol;
        const unsigned short* Bb = Uhb + (size_t)((kz * klen) >> 3) * 512 + lr * 8;
        float cv[8];
        #pragma unroll
        for (int j = 0; j < 8; ++j) cv[j] = A[(size_t)j * 8192];
        #pragma unroll 2
        for (int ks = 0; ks < kiters; ++ks) {
            int nxt = (ks + 1 < kiters) ? ks + 1 : ks;
            const float* np = A + (size_t)nxt * 32 * 8192;
            float nv[8];
            #pragma unroll
            for (int j = 0; j < 8; ++j) nv[j] = np[(size_t)j * 8192];
            union { bf16x8 v; unsigned u[4]; } af;
            #pragma unroll
            for (int qq = 0; qq < 4; ++qq)
                af.u[qq] = f2bf1(cv[2*qq]) | (f2bf1(cv[2*qq+1]) << 16);
            const unsigned short* bp = Bb + (size_t)(ks * 4 + lg) * 512;
            #pragma unroll
            for (int c = 0; c < 4; ++c) {
                bf16x8 bf = *(const bf16x8*)(bp + c * 128);
                acc[c] = __builtin_amdgcn_mfma_f32_16x16x32_bf16(af.v, bf, acc[c], 0, 0, 0);
            }
            #pragma unroll
            for (int j = 0; j < 8; ++j) cv[j] = nv[j];
        }
        float* out = Qp + (size_t)(kz * 8192 + tile * 64 + w * 16 + lg * 4) * 64 + lr;
        #pragma unroll
        for (int c = 0; c < 4; ++c) {
            #pragma unroll
            for (int j = 0; j < 4; ++j) out[j * 64 + c * 16] = acc[c][j];
        }
    }
}

// ------------------------------------------------------- S1: scores A and M
__global__ __launch_bounds__(256) void k_scoreAM(
    const int* __restrict__ bu, const int* __restrict__ bi,
    const float* __restrict__ Uh, const float* __restrict__ Vh,
    const float* __restrict__ W1A, const float* __restrict__ b1A,
    const float* __restrict__ w2A, const float* __restrict__ b2A,
    const float* __restrict__ W1M, const float* __restrict__ b1M,
    const float* __restrict__ w2M, const float* __restrict__ b2M,
    float* __restrict__ sA, float* __restrict__ sM)
{
    int gt = blockIdx.x * 256 + threadIdx.x;
    int wid = gt >> 6, lane = gt & 63;
    int b0 = wid * 2;
    float ub[2], vb[2];
    #pragma unroll
    for (int j = 0; j < 2; ++j) {
        ub[j] = Uh[(size_t)bu[b0 + j] * 64 + lane];
        vb[j] = Vh[(size_t)bi[b0 + j] * 64 + lane];
    }
    float hA[2], hM[2];
    #pragma unroll
    for (int j = 0; j < 2; ++j) { hA[j] = b1A[lane]; hM[j] = b1M[lane]; }
    for (int k = 0; k < 64; ++k) {
        float wa0 = W1A[k * 64 + lane], wa1 = W1A[(64 + k) * 64 + lane];
        float wm0 = W1M[k * 64 + lane], wm1 = W1M[(64 + k) * 64 + lane];
        #pragma unroll
        for (int j = 0; j < 2; ++j) {
            float sv = __shfl(vb[j], k), su = __shfl(ub[j], k);
            hA[j] += sv * wa0 + su * wa1;   // cat(Vb, Ub)
            hM[j] += su * wm0 + sv * wm1;   // cat(Ub, Vb)
        }
    }
    float w2a = w2A[lane], w2m = w2M[lane];
    #pragma unroll
    for (int j = 0; j < 2; ++j) {
        float sa = wsum(fmaxf(hA[j], 0.f) * w2a);
        float sm = wsum(fmaxf(hM[j], 0.f) * w2m);
        if (lane == 0) { sA[b0 + j] = sa + b2A[0]; sM[b0 + j] = sm + b2M[0]; }
    }
}

// ------------------------------------------------- S2: H_I and B-scores
__global__ __launch_bounds__(256) void k_HI_scoreB(
    const float* __restrict__ PpI, const float* __restrict__ sA,
    const int* __restrict__ bu, const float* __restrict__ Uh,
    const float* __restrict__ W_I, const float* __restrict__ b_I,
    const float* __restrict__ W1B, const float* __restrict__ b1B,
    const float* __restrict__ w2B, const float* __restrict__ b2B,
    float* __restrict__ HI, float* __restrict__ sB, int nkz)
{
    float m, inv;
    block_softmax_stats(sA, m, inv);
    int wid = blockIdx.x * 4 + (threadIdx.x >> 6);
    int lane = threadIdx.x & 63;
    int b0 = wid * 2;
    float p[2];
    #pragma unroll
    for (int j = 0; j < 2; ++j) {
        int b = b0 + j;
        float a = 0.f;
        for (int kz = 0; kz < nkz; ++kz)
            a += PpI[(size_t)(kz * 4096 + b) * 64 + lane];
        p[j] = a * (__expf(sA[b] - m) * inv);
    }
    float h[2];
    #pragma unroll
    for (int j = 0; j < 2; ++j) h[j] = b_I[lane];
    for (int k = 0; k < 64; ++k) {
        float wv = W_I[k * 64 + lane];
        #pragma unroll
        for (int j = 0; j < 2; ++j) h[j] += __shfl(p[j], k) * wv;
    }
    float ub[2];
    #pragma unroll
    for (int j = 0; j < 2; ++j) {
        h[j] = fmaxf(h[j], 0.f);
        HI[(size_t)(b0 + j) * 64 + lane] = h[j];
        ub[j] = Uh[(size_t)bu[b0 + j] * 64 + lane];
    }
    float h2[2];
    #pragma unroll
    for (int j = 0; j < 2; ++j) h2[j] = b1B[lane];
    for (int k = 0; k < 64; ++k) {
        float w0 = W1B[k * 64 + lane], w1 = W1B[(64 + k) * 64 + lane];
        #pragma unroll
        for (int j = 0; j < 2; ++j) h2[j] += __shfl(h[j], k) * w0 + __shfl(ub[j], k) * w1;
    }
    float w2 = w2B[lane];
    #pragma unroll
    for (int j = 0; j < 2; ++j) {
        float sv = wsum(fmaxf(h2[j], 0.f) * w2);
        if (lane == 0) sB[b0 + j] = sv + b2B[0];
    }
}

// ------------------------------------------------- S3: H_S then H
__global__ __launch_bounds__(256) void k_HS_H(
    const float* __restrict__ PpS, const float* __restrict__ sB,
    const float* __restrict__ HI,
    const float* __restrict__ W_Sm, const float* __restrict__ b_Sm,
    const float* __restrict__ Wc0, const float* __restrict__ bc0,
    const float* __restrict__ Wc1, const float* __restrict__ bc1,
    float* __restrict__ Hout, int nkz)
{
    float m, inv;
    block_softmax_stats(sB, m, inv);
    int wid = blockIdx.x * 4 + (threadIdx.x >> 6);
    int lane = threadIdx.x & 63;
    int b0 = wid * 2;
    float p[2];
    #pragma unroll
    for (int j = 0; j < 2; ++j) {
        int b = b0 + j;
        float a = 0.f;
        for (int kz = 0; kz < nkz; ++kz)
            a += PpS[(size_t)(kz * 4096 + b) * 64 + lane];
        p[j] = a * (__expf(sB[b] - m) * inv);
    }
    float hs[2];
    #pragma unroll
    for (int j = 0; j < 2; ++j) hs[j] = b_Sm[lane];
    for (int k = 0; k < 64; ++k) {
        float wv = W_Sm[k * 64 + lane];
        #pragma unroll
        for (int j = 0; j < 2; ++j) hs[j] += __shfl(p[j], k) * wv;
    }
    float hi[2];
    #pragma unroll
    for (int j = 0; j < 2; ++j) {
        hs[j] = fmaxf(hs[j], 0.f);
        hi[j] = HI[(size_t)(b0 + j) * 64 + lane];
    }
    float h0[2];
    #pragma unroll
    for (int j = 0; j < 2; ++j) h0[j] = bc0[lane];
    for (int k = 0; k < 64; ++k) {
        float w0 = Wc0[k * 64 + lane], w1 = Wc0[(64 + k) * 64 + lane];
        #pragma unroll
        for (int j = 0; j < 2; ++j) h0[j] += __shfl(hi[j], k) * w0 + __shfl(hs[j], k) * w1;
    }
    #pragma unroll
    for (int j = 0; j < 2; ++j) h0[j] = fmaxf(h0[j], 0.f);
    float h1[2];
    #pragma unroll
    for (int j = 0; j < 2; ++j) h1[j] = bc1[lane];
    for (int k = 0; k < 64; ++k) {
        float wv = Wc1[k * 64 + lane];
        #pragma unroll
        for (int j = 0; j < 2; ++j) h1[j] += __shfl(h0[j], k) * wv;
    }
    #pragma unroll
    for (int j = 0; j < 2; ++j) Hout[(size_t)(b0 + j) * 64 + lane] = fmaxf(h1[j], 0.f);
}

// ------------------------------------------------- S4: Z then G (output)
__global__ __launch_bounds__(256) void k_Z_G(
    const float* __restrict__ Qp, const float* __restrict__ sM,
    const int* __restrict__ bi, const float* __restrict__ H,
    const float* __restrict__ W_Z, const float* __restrict__ b_Z,
    const float* __restrict__ Wg0, const float* __restrict__ bg0,
    const float* __restrict__ Wg1, const float* __restrict__ bg1,
    float* __restrict__ G, int nkz)
{
    float m, inv;
    block_softmax_stats(sM, m, inv);
    int wid = blockIdx.x * 4 + (threadIdx.x >> 6);
    int lane = threadIdx.x & 63;
    int b0 = wid * 2;
    float p[2];
    #pragma unroll
    for (int j = 0; j < 2; ++j) {
        int b = b0 + j;
        int it = bi[b];
        float a = 0.f;
        for (int kz = 0; kz < nkz; ++kz)
            a += Qp[(size_t)(kz * 8192 + it) * 64 + lane];
        p[j] = a * (__expf(sM[b] - m) * inv);
    }
    float z[2];
    #pragma unroll
    for (int j = 0; j < 2; ++j) z[j] = b_Z[lane];
    for (int k = 0; k < 64; ++k) {
        float wv = W_Z[k * 64 + lane];
        #pragma unroll
        for (int j = 0; j < 2; ++j) z[j] += __shfl(p[j], k) * wv;
    }
    float hr[2];
    #pragma unroll
    for (int j = 0; j < 2; ++j) {
        z[j] = fmaxf(z[j], 0.f);
        hr[j] = H[(size_t)(b0 + j) * 64 + lane];
    }
    float g0[2];
    #pragma unroll
    for (int j = 0; j < 2; ++j) g0[j] = bg0[lane];
    for (int k = 0; k < 64; ++k) {
        float w0 = Wg0[k * 64 + lane], w1 = Wg0[(64 + k) * 64 + lane];
        #pragma unroll
        for (int j = 0; j < 2; ++j) g0[j] += __shfl(hr[j], k) * w0 + __shfl(z[j], k) * w1;
    }
    #pragma unroll
    for (int j = 0; j < 2; ++j) g0[j] = fmaxf(g0[j], 0.f);
    float g1[2];
    #pragma unroll
    for (int j = 0; j < 2; ++j) g1[j] = bg1[lane];
    for (int k = 0; k < 64; ++k) {
        float wv = Wg1[k * 64 + lane];
        #pragma unroll
        for (int j = 0; j < 2; ++j) g1[j] += __shfl(g0[j], k) * wv;
    }
    #pragma unroll
    for (int j = 0; j < 2; ++j) G[(size_t)(b0 + j) * 64 + lane] = fmaxf(g1[j], 0.f);
}

// ---------------------------------------------------------------------------
extern "C" void kernel_launch(void* const* d_in, const int* in_sizes, int n_in,
                              void* d_out, int out_size, void* d_ws, size_t ws_size,
                              hipStream_t stream)
{
    (void)in_sizes; (void)n_in; (void)out_size;
    const int*   bu  = (const int*)  d_in[0];
    const int*   bi  = (const int*)  d_in[1];
    const float* R   = (const float*)d_in[2];
    const float* S   = (const float*)d_in[3];
    const float* U   = (const float*)d_in[4];
    const float* V   = (const float*)d_in[5];
    const float* w_r = (const float*)d_in[6];
    const float* b_r = (const float*)d_in[7];
    const float* Wu0 = (const float*)d_in[8];
    const float* bu0 = (const float*)d_in[9];
    const float* Wu1 = (const float*)d_in[10];
    const float* bu1 = (const float*)d_in[11];
    const float* Wv0 = (const float*)d_in[12];
    const float* bv0 = (const float*)d_in[13];
    const float* Wv1 = (const float*)d_in[14];
    const float* bv1 = (const float*)d_in[15];
    const float* Wc0 = (const float*)d_in[16];
    const float* bc0 = (const float*)d_in[17];
    const float* Wc1 = (const float*)d_in[18];
    const float* bc1 = (const float*)d_in[19];
    const float* Wg0 = (const float*)d_in[20];
    const float* bg0 = (const float*)d_in[21];
    const float* Wg1 = (const float*)d_in[22];
    const float* bg1 = (const float*)d_in[23];
    const float* W_I = (const float*)d_in[24];
    const float* b_I = (const float*)d_in[25];
    const float* W_Sm= (const float*)d_in[26];
    const float* b_Sm= (const float*)d_in[27];
    const float* W1A = (const float*)d_in[28];
    const float* b1A = (const float*)d_in[29];
    const float* w2A = (const float*)d_in[30];
    const float* b2A = (const float*)d_in[31];
    const float* W1B = (const float*)d_in[32];
    const float* b1B = (const float*)d_in[33];
    const float* w2B = (const float*)d_in[34];
    const float* b2B = (const float*)d_in[35];
    const float* W1M = (const float*)d_in[36];
    const float* b1M = (const float*)d_in[37];
    const float* w2M = (const float*)d_in[38];
    const float* b2M = (const float*)d_in[39];
    const float* W_Z = (const float*)d_in[40];
    const float* b_Z = (const float*)d_in[41];

    const int nkz  = (ws_size >= (42ull << 20)) ? 8 : 4;
    const int klen = 8192 / nkz;

    char* ws = (char*)d_ws;
    size_t off = 0;
    float*          Uh  = (float*)(ws + off);          off += 2ull << 20;
    float*          Vh  = (float*)(ws + off);          off += 2ull << 20;
    unsigned short* Uhb = (unsigned short*)(ws + off); off += 1ull << 20;
    unsigned short* Vhb = (unsigned short*)(ws + off); off += 1ull << 20;
    float*          PpI = (float*)(ws + off);          off += (size_t)nkz << 20;
    float*          PpS = (float*)(ws + off);          off += (size_t)nkz << 20;
    float*          Qp  = (float*)(ws + off);          off += (size_t)(2 * nkz) << 20;
    float*          sA  = (float*)(ws + off);
    float*          sM  = sA + 4096;
    float*          sB  = sA + 8192;                   off += 3 * 4096 * 4 + 4096;
    float*          HI  = (float*)(ws + off);          off += 1ull << 20;
    float*          Hh  = (float*)(ws + off);

    k_mlp<<<1024, 256, 0, stream>>>(U, V, w_r, b_r, Wu0, bu0, Wu1, bu1,
                                    Wv0, bv0, Wv1, bv1, Uh, Vh, Uhb, Vhb);
    int gP = nkz * 64, gQ = nkz * 128;
    k_gemm<<<2 * gP + gQ, 256, 0, stream>>>(R, S, bu, Uhb, Vhb, PpI, PpS, Qp,
                                            nkz, klen);
    k_scoreAM<<<512, 256, 0, stream>>>(bu, bi, Uh, Vh, W1A, b1A, w2A, b2A,
                                       W1M, b1M, w2M, b2M, sA, sM);
    k_HI_scoreB<<<512, 256, 0, stream>>>(PpI, sA, bu, Uh, W_I, b_I,
                                         W1B, b1B, w2B, b2B, HI, sB, nkz);
    k_HS_H<<<512, 256, 0, stream>>>(PpS, sB, HI, W_Sm, b_Sm, Wc0, bc0, Wc1, bc1,
                                    Hh, nkz);
    k_Z_G<<<512, 256, 0, stream>>>(Qp, sM, bi, Hh, W_Z, b_Z, Wg0, bg0, Wg1, bg1,
                                   (float*)d_out, nkz);
}

// Round 3
// 224.073 us; speedup vs baseline: 1.0800x; 1.0779x over previous
//
#include <hip/hip_runtime.h>
#include <stdint.h>

// ---------------------------------------------------------------------------
// GraphRec forward, MI355X.
//  K1 k_mlp      : e_r + 2-layer MLPs -> Uh,Vh (f32) + blocked bf16 copies
//  K2 k_gemmQ    : Q = R^T@Uh via LDS-staged tiles (global_load_lds, dbuf)
//  K3 k_gemmP    : P_I = R[bu]@Vh, P_S = S[bu]@Uh (depth-4 reg pipeline)
//  S1 k_scoreAM  : pre-softmax scores sA (cat(Vb,Ub)) and sM (cat(Ub,Vb))
//  S2 k_HI_scoreB: [softmax-A in-block] H_I = relu((A.P_I)@W_I+b); sB
//  S3 k_HS_H     : [softmax-B] H_S = relu((B.P_S)@W_Sm+b); H = MLP(cat(H_I,H_S))
//  S4 k_Z_G      : [softmax-M] Z = relu((M.Q[bi])@W_Z+b); G = MLP(cat(H,Z))
// ---------------------------------------------------------------------------

typedef short bf16x8 __attribute__((ext_vector_type(8)));
typedef float f32x4 __attribute__((ext_vector_type(4)));

#define NKZ    8
#define KLEN   1024          // 8192 / NKZ
#define KITERS 32            // KLEN / 32

__device__ __forceinline__ unsigned f2bf1(float f) {
    unsigned x = __float_as_uint(f);
    return (x + 0x7FFFu + ((x >> 16) & 1u)) >> 16;   // RNE f32->bf16
}

__device__ __forceinline__ float wsum(float v) {
    #pragma unroll
    for (int o = 32; o; o >>= 1) v += __shfl_xor(v, o);
    return v;
}

// block-wide softmax stats over a 4096-vector (256-thread block)
__device__ __forceinline__ void block_softmax_stats(const float* __restrict__ s,
                                                    float& m, float& inv) {
    __shared__ float r1[4];
    __shared__ float r2[4];
    int t = threadIdx.x, lane = t & 63, wv = t >> 6;
    float lm = -3.4e38f;
    #pragma unroll
    for (int i = 0; i < 16; ++i) lm = fmaxf(lm, s[t + 256 * i]);
    #pragma unroll
    for (int o = 32; o; o >>= 1) lm = fmaxf(lm, __shfl_xor(lm, o));
    if (lane == 0) r1[wv] = lm;
    __syncthreads();
    m = fmaxf(fmaxf(r1[0], r1[1]), fmaxf(r1[2], r1[3]));
    float ls = 0.f;
    #pragma unroll
    for (int i = 0; i < 16; ++i) ls += __expf(s[t + 256 * i] - m);
    ls = wsum(ls);
    if (lane == 0) r2[wv] = ls;
    __syncthreads();
    inv = 1.f / (r2[0] + r2[1] + r2[2] + r2[3]);
}

// ---------------------------------------------------------------- K1: MLPs
__global__ __launch_bounds__(256) void k_mlp(
    const float* __restrict__ U, const float* __restrict__ V,
    const float* __restrict__ w_r, const float* __restrict__ b_r,
    const float* __restrict__ Wu0, const float* __restrict__ bu0,
    const float* __restrict__ Wu1, const float* __restrict__ bu1,
    const float* __restrict__ Wv0, const float* __restrict__ bv0,
    const float* __restrict__ Wv1, const float* __restrict__ bv1,
    float* __restrict__ Uh, float* __restrict__ Vh,
    unsigned short* __restrict__ Uhb, unsigned short* __restrict__ Vhb)
{
    int gt = blockIdx.x * 256 + threadIdx.x;
    int wid = gt >> 6;
    int lane = gt & 63;

    float er = b_r[lane];
    #pragma unroll
    for (int s = 0; s < 5; ++s) er += (float)(s + 1) * w_r[s * 64 + lane];

    const int isV = (wid >= 2048);
    const float* X  = isV ? V   : U;
    const float* W0 = isV ? Wv0 : Wu0;
    const float* B0 = isV ? bv0 : bu0;
    const float* W1 = isV ? Wv1 : Wu1;
    const float* B1 = isV ? bv1 : bu1;
    float* Hout          = isV ? Vh  : Uh;
    unsigned short* Hb   = isV ? Vhb : Uhb;
    int r0 = (wid & 2047) * 4;

    float x[4];
    #pragma unroll
    for (int j = 0; j < 4; ++j) x[j] = X[(r0 + j) * 64 + lane];

    float h0c = B0[lane];
    for (int k = 0; k < 64; ++k) h0c += __shfl(er, k) * W0[(64 + k) * 64 + lane];

    float h0[4];
    #pragma unroll
    for (int j = 0; j < 4; ++j) h0[j] = h0c;
    for (int k = 0; k < 64; ++k) {
        float wv = W0[k * 64 + lane];
        #pragma unroll
        for (int j = 0; j < 4; ++j) h0[j] += __shfl(x[j], k) * wv;
    }
    #pragma unroll
    for (int j = 0; j < 4; ++j) h0[j] = fmaxf(h0[j], 0.f);

    float h1[4];
    #pragma unroll
    for (int j = 0; j < 4; ++j) h1[j] = B1[lane];
    for (int k = 0; k < 64; ++k) {
        float wv = W1[k * 64 + lane];
        #pragma unroll
        for (int j = 0; j < 4; ++j) h1[j] += __shfl(h0[j], k) * wv;
    }
    #pragma unroll
    for (int j = 0; j < 4; ++j) {
        h1[j] = fmaxf(h1[j], 0.f);
        Hout[(r0 + j) * 64 + lane] = h1[j];
    }
    // blocked bf16: element (r,d) at (r>>3)*512 + (d>>4)*128 + (d&15)*8 + (r&7)
    unsigned pw[2];
    #pragma unroll
    for (int q = 0; q < 2; ++q) pw[q] = f2bf1(h1[2*q]) | (f2bf1(h1[2*q+1]) << 16);
    unsigned short* dst = Hb + (size_t)(r0 >> 3) * 512 + (lane >> 4) * 128
                        + (lane & 15) * 8 + (r0 & 7);
    *(uint2*)dst = make_uint2(pw[0], pw[1]);
}

// ------------------------------------------------------- K2: Q = R^T @ Uh
// grid = 128 i-tiles(64 wide) x NKZ k-slabs(1024 u). LDS double-buffered
// [32u][64i] f32 tiles staged via global_load_lds (16B), 2-phase barrier loop.
__global__ __launch_bounds__(256) void k_gemmQ(
    const float* __restrict__ R,
    const unsigned short* __restrict__ Uhb,
    float* __restrict__ Qp)
{
    __shared__ float lds[2][2048];       // 2 x 8 KB
    const int tile = blockIdx.x & 127;
    const int kz   = blockIdx.x >> 7;
    const int i0 = tile * 64;
    const int u0 = kz * KLEN;
    const int t = threadIdx.x;
    const int w = t >> 6, l = t & 63, lg = l >> 4, lr = l & 15;

    f32x4 acc[4] = {};

    // staging map: issue q, thread t -> LDS float off (q*256+t)*4,
    // row u_rel = q*16 + (t>>4), cols (t&15)*4 .. +4
    const float* gbase = R + ((size_t)u0 + (t >> 4)) * 8192 + i0 + (t & 15) * 4;

    // prologue: stage 0
    #pragma unroll
    for (int q = 0; q < 2; ++q) {
        const float* g = gbase + (size_t)(q * 16) * 8192;
        __builtin_amdgcn_global_load_lds(
            (const __attribute__((address_space(1))) void*)g,
            (__attribute__((address_space(3))) void*)&lds[0][(q * 256 + t) * 4],
            16, 0, 0);
    }
    __syncthreads();

    const int iloc = w * 16 + lr;
    for (int s = 0; s < KITERS; ++s) {
        if (s + 1 < KITERS) {
            int nb = (s + 1) & 1;
            #pragma unroll
            for (int q = 0; q < 2; ++q) {
                const float* g = gbase + (size_t)((s + 1) * 32 + q * 16) * 8192;
                __builtin_amdgcn_global_load_lds(
                    (const __attribute__((address_space(1))) void*)g,
                    (__attribute__((address_space(3))) void*)&lds[nb][(q * 256 + t) * 4],
                    16, 0, 0);
            }
        }
        const float* Lb = lds[s & 1];
        float av[8];
        #pragma unroll
        for (int j = 0; j < 8; ++j) av[j] = Lb[(8 * lg + j) * 64 + iloc];
        union { bf16x8 v; unsigned u[4]; } af;
        #pragma unroll
        for (int q = 0; q < 4; ++q)
            af.u[q] = f2bf1(av[2*q]) | (f2bf1(av[2*q+1]) << 16);
        const unsigned short* bp = Uhb + (size_t)((u0 >> 3) + s * 4 + lg) * 512 + lr * 8;
        #pragma unroll
        for (int c = 0; c < 4; ++c) {
            bf16x8 bf = *(const bf16x8*)(bp + c * 128);
            acc[c] = __builtin_amdgcn_mfma_f32_16x16x32_bf16(af.v, bf, acc[c], 0, 0, 0);
        }
        __syncthreads();
    }

    float* out = Qp + (size_t)(kz * 8192 + tile * 64 + w * 16 + lg * 4) * 64 + lr;
    #pragma unroll
    for (int c = 0; c < 4; ++c) {
        #pragma unroll
        for (int j = 0; j < 4; ++j) out[j * 64 + c * 16] = acc[c][j];
    }
}

// ------------------------------------------- K3: P_I and P_S (row gathers)
// blocks [0, gP): P_I   A = R[bu rows];  [gP, 2gP): P_S  A = S[bu rows]
// depth-4 register pipeline, compile-time trip counts.
__global__ __launch_bounds__(256) void k_gemmP(
    const float* __restrict__ R, const float* __restrict__ S,
    const int* __restrict__ bu,
    const unsigned short* __restrict__ Uhb, const unsigned short* __restrict__ Vhb,
    float* __restrict__ PpI, float* __restrict__ PpS)
{
    const int gP = NKZ * 64;
    int bid = blockIdx.x;
    const int isS = bid >= gP;
    int q = isS ? bid - gP : bid;
    int tile = q & 63, kz = q >> 6;
    int tid = threadIdx.x;
    int w = tid >> 6, l = tid & 63;
    int lg = l >> 4, lr = l & 15;

    int brow = tile * 64 + w * 16 + lr;
    int ridx = bu[brow];
    const float* A = (isS ? S : R) + (size_t)ridx * 8192 + kz * KLEN + lg * 8;
    const unsigned short* Bb = (isS ? Uhb : Vhb)
                             + (size_t)((kz * KLEN) >> 3) * 512 + lr * 8;

    f32x4 acc[4] = {};
    f32x4 b0[4], b1[4];
    #pragma unroll
    for (int d = 0; d < 4; ++d) {
        b0[d] = ((const f32x4*)(A + d * 32))[0];
        b1[d] = ((const f32x4*)(A + d * 32))[1];
    }

    #pragma unroll 4
    for (int ks = 0; ks < KITERS - 4; ++ks) {
        const int slot = ks & 3;
        union { bf16x8 v; unsigned u[4]; } af;
        af.u[0] = f2bf1(b0[slot].x) | (f2bf1(b0[slot].y) << 16);
        af.u[1] = f2bf1(b0[slot].z) | (f2bf1(b0[slot].w) << 16);
        af.u[2] = f2bf1(b1[slot].x) | (f2bf1(b1[slot].y) << 16);
        af.u[3] = f2bf1(b1[slot].z) | (f2bf1(b1[slot].w) << 16);
        b0[slot] = ((const f32x4*)(A + (ks + 4) * 32))[0];
        b1[slot] = ((const f32x4*)(A + (ks + 4) * 32))[1];
        const unsigned short* bp = Bb + (size_t)(ks * 4 + lg) * 512;
        #pragma unroll
        for (int c = 0; c < 4; ++c) {
            bf16x8 bf = *(const bf16x8*)(bp + c * 128);
            acc[c] = __builtin_amdgcn_mfma_f32_16x16x32_bf16(af.v, bf, acc[c], 0, 0, 0);
        }
    }
    #pragma unroll
    for (int ks = KITERS - 4; ks < KITERS; ++ks) {
        const int slot = ks & 3;
        union { bf16x8 v; unsigned u[4]; } af;
        af.u[0] = f2bf1(b0[slot].x) | (f2bf1(b0[slot].y) << 16);
        af.u[1] = f2bf1(b0[slot].z) | (f2bf1(b0[slot].w) << 16);
        af.u[2] = f2bf1(b1[slot].x) | (f2bf1(b1[slot].y) << 16);
        af.u[3] = f2bf1(b1[slot].z) | (f2bf1(b1[slot].w) << 16);
        const unsigned short* bp = Bb + (size_t)(ks * 4 + lg) * 512;
        #pragma unroll
        for (int c = 0; c < 4; ++c) {
            bf16x8 bf = *(const bf16x8*)(bp + c * 128);
            acc[c] = __builtin_amdgcn_mfma_f32_16x16x32_bf16(af.v, bf, acc[c], 0, 0, 0);
        }
    }

    float* out = (isS ? PpS : PpI)
               + (size_t)(kz * 4096 + tile * 64 + w * 16 + lg * 4) * 64 + lr;
    #pragma unroll
    for (int c = 0; c < 4; ++c) {
        #pragma unroll
        for (int j = 0; j < 4; ++j) out[j * 64 + c * 16] = acc[c][j];
    }
}

// ------------------------------------------------------- S1: scores A and M
__global__ __launch_bounds__(256) void k_scoreAM(
    const int* __restrict__ bu, const int* __restrict__ bi,
    const float* __restrict__ Uh, const float* __restrict__ Vh,
    const float* __restrict__ W1A, const float* __restrict__ b1A,
    const float* __restrict__ w2A, const float* __restrict__ b2A,
    const float* __restrict__ W1M, const float* __restrict__ b1M,
    const float* __restrict__ w2M, const float* __restrict__ b2M,
    float* __restrict__ sA, float* __restrict__ sM)
{
    int gt = blockIdx.x * 256 + threadIdx.x;
    int wid = gt >> 6, lane = gt & 63;
    int b0 = wid * 2;
    float ub[2], vb[2];
    #pragma unroll
    for (int j = 0; j < 2; ++j) {
        ub[j] = Uh[(size_t)bu[b0 + j] * 64 + lane];
        vb[j] = Vh[(size_t)bi[b0 + j] * 64 + lane];
    }
    float hA[2], hM[2];
    #pragma unroll
    for (int j = 0; j < 2; ++j) { hA[j] = b1A[lane]; hM[j] = b1M[lane]; }
    for (int k = 0; k < 64; ++k) {
        float wa0 = W1A[k * 64 + lane], wa1 = W1A[(64 + k) * 64 + lane];
        float wm0 = W1M[k * 64 + lane], wm1 = W1M[(64 + k) * 64 + lane];
        #pragma unroll
        for (int j = 0; j < 2; ++j) {
            float sv = __shfl(vb[j], k), su = __shfl(ub[j], k);
            hA[j] += sv * wa0 + su * wa1;   // cat(Vb, Ub)
            hM[j] += su * wm0 + sv * wm1;   // cat(Ub, Vb)
        }
    }
    float w2a = w2A[lane], w2m = w2M[lane];
    #pragma unroll
    for (int j = 0; j < 2; ++j) {
        float sa = wsum(fmaxf(hA[j], 0.f) * w2a);
        float sm = wsum(fmaxf(hM[j], 0.f) * w2m);
        if (lane == 0) { sA[b0 + j] = sa + b2A[0]; sM[b0 + j] = sm + b2M[0]; }
    }
}

// ------------------------------------------------- S2: H_I and B-scores
__global__ __launch_bounds__(256) void k_HI_scoreB(
    const float* __restrict__ PpI, const float* __restrict__ sA,
    const int* __restrict__ bu, const float* __restrict__ Uh,
    const float* __restrict__ W_I, const float* __restrict__ b_I,
    const float* __restrict__ W1B, const float* __restrict__ b1B,
    const float* __restrict__ w2B, const float* __restrict__ b2B,
    float* __restrict__ HI, float* __restrict__ sB)
{
    float m, inv;
    block_softmax_stats(sA, m, inv);
    int wid = blockIdx.x * 4 + (threadIdx.x >> 6);
    int lane = threadIdx.x & 63;
    int b0 = wid * 2;
    float p[2];
    #pragma unroll
    for (int j = 0; j < 2; ++j) {
        int b = b0 + j;
        float a = 0.f;
        #pragma unroll
        for (int kz = 0; kz < NKZ; ++kz)
            a += PpI[(size_t)(kz * 4096 + b) * 64 + lane];
        p[j] = a * (__expf(sA[b] - m) * inv);
    }
    float h[2];
    #pragma unroll
    for (int j = 0; j < 2; ++j) h[j] = b_I[lane];
    for (int k = 0; k < 64; ++k) {
        float wv = W_I[k * 64 + lane];
        #pragma unroll
        for (int j = 0; j < 2; ++j) h[j] += __shfl(p[j], k) * wv;
    }
    float ub[2];
    #pragma unroll
    for (int j = 0; j < 2; ++j) {
        h[j] = fmaxf(h[j], 0.f);
        HI[(size_t)(b0 + j) * 64 + lane] = h[j];
        ub[j] = Uh[(size_t)bu[b0 + j] * 64 + lane];
    }
    float h2[2];
    #pragma unroll
    for (int j = 0; j < 2; ++j) h2[j] = b1B[lane];
    for (int k = 0; k < 64; ++k) {
        float w0 = W1B[k * 64 + lane], w1 = W1B[(64 + k) * 64 + lane];
        #pragma unroll
        for (int j = 0; j < 2; ++j) h2[j] += __shfl(h[j], k) * w0 + __shfl(ub[j], k) * w1;
    }
    float w2 = w2B[lane];
    #pragma unroll
    for (int j = 0; j < 2; ++j) {
        float sv = wsum(fmaxf(h2[j], 0.f) * w2);
        if (lane == 0) sB[b0 + j] = sv + b2B[0];
    }
}

// ------------------------------------------------- S3: H_S then H
__global__ __launch_bounds__(256) void k_HS_H(
    const float* __restrict__ PpS, const float* __restrict__ sB,
    const float* __restrict__ HI,
    const float* __restrict__ W_Sm, const float* __restrict__ b_Sm,
    const float* __restrict__ Wc0, const float* __restrict__ bc0,
    const float* __restrict__ Wc1, const float* __restrict__ bc1,
    float* __restrict__ Hout)
{
    float m, inv;
    block_softmax_stats(sB, m, inv);
    int wid = blockIdx.x * 4 + (threadIdx.x >> 6);
    int lane = threadIdx.x & 63;
    int b0 = wid * 2;
    float p[2];
    #pragma unroll
    for (int j = 0; j < 2; ++j) {
        int b = b0 + j;
        float a = 0.f;
        #pragma unroll
        for (int kz = 0; kz < NKZ; ++kz)
            a += PpS[(size_t)(kz * 4096 + b) * 64 + lane];
        p[j] = a * (__expf(sB[b] - m) * inv);
    }
    float hs[2];
    #pragma unroll
    for (int j = 0; j < 2; ++j) hs[j] = b_Sm[lane];
    for (int k = 0; k < 64; ++k) {
        float wv = W_Sm[k * 64 + lane];
        #pragma unroll
        for (int j = 0; j < 2; ++j) hs[j] += __shfl(p[j], k) * wv;
    }
    float hi[2];
    #pragma unroll
    for (int j = 0; j < 2; ++j) {
        hs[j] = fmaxf(hs[j], 0.f);
        hi[j] = HI[(size_t)(b0 + j) * 64 + lane];
    }
    float h0[2];
    #pragma unroll
    for (int j = 0; j < 2; ++j) h0[j] = bc0[lane];
    for (int k = 0; k < 64; ++k) {
        float w0 = Wc0[k * 64 + lane], w1 = Wc0[(64 + k) * 64 + lane];
        #pragma unroll
        for (int j = 0; j < 2; ++j) h0[j] += __shfl(hi[j], k) * w0 + __shfl(hs[j], k) * w1;
    }
    #pragma unroll
    for (int j = 0; j < 2; ++j) h0[j] = fmaxf(h0[j], 0.f);
    float h1[2];
    #pragma unroll
    for (int j = 0; j < 2; ++j) h1[j] = bc1[lane];
    for (int k = 0; k < 64; ++k) {
        float wv = Wc1[k * 64 + lane];
        #pragma unroll
        for (int j = 0; j < 2; ++j) h1[j] += __shfl(h0[j], k) * wv;
    }
    #pragma unroll
    for (int j = 0; j < 2; ++j) Hout[(size_t)(b0 + j) * 64 + lane] = fmaxf(h1[j], 0.f);
}

// ------------------------------------------------- S4: Z then G (output)
__global__ __launch_bounds__(256) void k_Z_G(
    const float* __restrict__ Qp, const float* __restrict__ sM,
    const int* __restrict__ bi, const float* __restrict__ H,
    const float* __restrict__ W_Z, const float* __restrict__ b_Z,
    const float* __restrict__ Wg0, const float* __restrict__ bg0,
    const float* __restrict__ Wg1, const float* __restrict__ bg1,
    float* __restrict__ G)
{
    float m, inv;
    block_softmax_stats(sM, m, inv);
    int wid = blockIdx.x * 4 + (threadIdx.x >> 6);
    int lane = threadIdx.x & 63;
    int b0 = wid * 2;
    float p[2];
    #pragma unroll
    for (int j = 0; j < 2; ++j) {
        int b = b0 + j;
        int it = bi[b];
        float a = 0.f;
        #pragma unroll
        for (int kz = 0; kz < NKZ; ++kz)
            a += Qp[(size_t)(kz * 8192 + it) * 64 + lane];
        p[j] = a * (__expf(sM[b] - m) * inv);
    }
    float z[2];
    #pragma unroll
    for (int j = 0; j < 2; ++j) z[j] = b_Z[lane];
    for (int k = 0; k < 64; ++k) {
        float wv = W_Z[k * 64 + lane];
        #pragma unroll
        for (int j = 0; j < 2; ++j) z[j] += __shfl(p[j], k) * wv;
    }
    float hr[2];
    #pragma unroll
    for (int j = 0; j < 2; ++j) {
        z[j] = fmaxf(z[j], 0.f);
        hr[j] = H[(size_t)(b0 + j) * 64 + lane];
    }
    float g0[2];
    #pragma unroll
    for (int j = 0; j < 2; ++j) g0[j] = bg0[lane];
    for (int k = 0; k < 64; ++k) {
        float w0 = Wg0[k * 64 + lane], w1 = Wg0[(64 + k) * 64 + lane];
        #pragma unroll
        for (int j = 0; j < 2; ++j) g0[j] += __shfl(hr[j], k) * w0 + __shfl(z[j], k) * w1;
    }
    #pragma unroll
    for (int j = 0; j < 2; ++j) g0[j] = fmaxf(g0[j], 0.f);
    float g1[2];
    #pragma unroll
    for (int j = 0; j < 2; ++j) g1[j] = bg1[lane];
    for (int k = 0; k < 64; ++k) {
        float wv = Wg1[k * 64 + lane];
        #pragma unroll
        for (int j = 0; j < 2; ++j) g1[j] += __shfl(g0[j], k) * wv;
    }
    #pragma unroll
    for (int j = 0; j < 2; ++j) G[(size_t)(b0 + j) * 64 + lane] = fmaxf(g1[j], 0.f);
}

// ---------------------------------------------------------------------------
extern "C" void kernel_launch(void* const* d_in, const int* in_sizes, int n_in,
                              void* d_out, int out_size, void* d_ws, size_t ws_size,
                              hipStream_t stream)
{
    (void)in_sizes; (void)n_in; (void)out_size; (void)ws_size;
    const int*   bu  = (const int*)  d_in[0];
    const int*   bi  = (const int*)  d_in[1];
    const float* R   = (const float*)d_in[2];
    const float* S   = (const float*)d_in[3];
    const float* U   = (const float*)d_in[4];
    const float* V   = (const float*)d_in[5];
    const float* w_r = (const float*)d_in[6];
    const float* b_r = (const float*)d_in[7];
    const float* Wu0 = (const float*)d_in[8];
    const float* bu0 = (const float*)d_in[9];
    const float* Wu1 = (const float*)d_in[10];
    const float* bu1 = (const float*)d_in[11];
    const float* Wv0 = (const float*)d_in[12];
    const float* bv0 = (const float*)d_in[13];
    const float* Wv1 = (const float*)d_in[14];
    const float* bv1 = (const float*)d_in[15];
    const float* Wc0 = (const float*)d_in[16];
    const float* bc0 = (const float*)d_in[17];
    const float* Wc1 = (const float*)d_in[18];
    const float* bc1 = (const float*)d_in[19];
    const float* Wg0 = (const float*)d_in[20];
    const float* bg0 = (const float*)d_in[21];
    const float* Wg1 = (const float*)d_in[22];
    const float* bg1 = (const float*)d_in[23];
    const float* W_I = (const float*)d_in[24];
    const float* b_I = (const float*)d_in[25];
    const float* W_Sm= (const float*)d_in[26];
    const float* b_Sm= (const float*)d_in[27];
    const float* W1A = (const float*)d_in[28];
    const float* b1A = (const float*)d_in[29];
    const float* w2A = (const float*)d_in[30];
    const float* b2A = (const float*)d_in[31];
    const float* W1B = (const float*)d_in[32];
    const float* b1B = (const float*)d_in[33];
    const float* w2B = (const float*)d_in[34];
    const float* b2B = (const float*)d_in[35];
    const float* W1M = (const float*)d_in[36];
    const float* b1M = (const float*)d_in[37];
    const float* w2M = (const float*)d_in[38];
    const float* b2M = (const float*)d_in[39];
    const float* W_Z = (const float*)d_in[40];
    const float* b_Z = (const float*)d_in[41];

    char* ws = (char*)d_ws;
    size_t off = 0;
    float*          Uh  = (float*)(ws + off);          off += 2ull << 20;
    float*          Vh  = (float*)(ws + off);          off += 2ull << 20;
    unsigned short* Uhb = (unsigned short*)(ws + off); off += 1ull << 20;
    unsigned short* Vhb = (unsigned short*)(ws + off); off += 1ull << 20;
    float*          PpI = (float*)(ws + off);          off += (size_t)NKZ << 20;
    float*          PpS = (float*)(ws + off);          off += (size_t)NKZ << 20;
    float*          Qp  = (float*)(ws + off);          off += (size_t)(2 * NKZ) << 20;
    float*          sA  = (float*)(ws + off);
    float*          sM  = sA + 4096;
    float*          sB  = sA + 8192;                   off += 3 * 4096 * 4 + 4096;
    float*          HI  = (float*)(ws + off);          off += 1ull << 20;
    float*          Hh  = (float*)(ws + off);

    k_mlp<<<1024, 256, 0, stream>>>(U, V, w_r, b_r, Wu0, bu0, Wu1, bu1,
                                    Wv0, bv0, Wv1, bv1, Uh, Vh, Uhb, Vhb);
    k_gemmQ<<<128 * NKZ, 256, 0, stream>>>(R, Uhb, Qp);
    k_gemmP<<<2 * NKZ * 64, 256, 0, stream>>>(R, S, bu, Uhb, Vhb, PpI, PpS);
    k_scoreAM<<<512, 256, 0, stream>>>(bu, bi, Uh, Vh, W1A, b1A, w2A, b2A,
                                       W1M, b1M, w2M, b2M, sA, sM);
    k_HI_scoreB<<<512, 256, 0, stream>>>(PpI, sA, bu, Uh, W_I, b_I,
                                         W1B, b1B, w2B, b2B, HI, sB);
    k_HS_H<<<512, 256, 0, stream>>>(PpS, sB, HI, W_Sm, b_Sm, Wc0, bc0, Wc1, bc1,
                                    Hh);
    k_Z_G<<<512, 256, 0, stream>>>(Qp, sM, bi, Hh, W_Z, b_Z, Wg0, bg0, Wg1, bg1,
                                   (float*)d_out);
}